// Round 12
// baseline (97.945 us; speedup 1.0000x reference)
//
#include <hip/hip_runtime.h>
#include <hip/hip_bf16.h>

static constexpr int N = 100000;   // nodes
static constexpr int E = 1000000;  // edges
static constexpr int D = 64;       // feature dim
static constexpr int NB = 391;     // dst buckets of 256 nodes (391*256 >= N)
static constexpr int CAP = 3072;   // per-bucket edge capacity (mean 2560, ~+10 sigma)
static constexpr int PART_EPT = 8;
static constexpr int PART_CHUNK = 256 * PART_EPT;                        // 2048
static constexpr int PART_BLOCKS = (E + PART_CHUNK - 1) / PART_CHUNK;    // 489
static constexpr int LIN_BLOCKS = (N + 63) / 64;                         // 1563

typedef __attribute__((ext_vector_type(8))) short bf16x8;
typedef __attribute__((ext_vector_type(4))) float f32x4;

__device__ inline ushort f2bf(float f) {     // RNE f32 -> bf16 bits
    unsigned u = __float_as_uint(f);
    return (ushort)((u + 0x7fffu + ((u >> 16) & 1u)) >> 16);
}

// ---- init: zero gcur, W f32->bf16, dummy row N, dis[N] --------------------
__global__ __launch_bounds__(256) void k_init(const float* __restrict__ w,
                                              int* __restrict__ gcur,
                                              float* __restrict__ dis,
                                              ushort* __restrict__ wbf,
                                              ushort* __restrict__ hb) {
    int tid = threadIdx.x;
    int i0 = tid * 16;
#pragma unroll
    for (int c = 0; c < 4; ++c) {
        float4 v = *reinterpret_cast<const float4*>(w + i0 + c * 4);
        ushort4 o;
        o.x = f2bf(v.x); o.y = f2bf(v.y); o.z = f2bf(v.z); o.w = f2bf(v.w);
        *reinterpret_cast<ushort4*>(wbf + i0 + c * 4) = o;
    }
    for (int b = tid; b < NB; b += 256) gcur[b] = 0;
    if (tid == 0) dis[N] = 0.f;
    if (tid < 32) reinterpret_cast<int*>(hb + N * D)[tid] = 0;   // zero row N
}

// ---- K1: bucket partition (blocks [0,PART_BLOCKS)) ∪ linear (rest) --------
__global__ __launch_bounds__(256) void k_partlin(const int* __restrict__ ei,
                                                 const float* __restrict__ x,
                                                 const ushort* __restrict__ wbf,
                                                 int* __restrict__ gcur,
                                                 int* __restrict__ part,
                                                 ushort* __restrict__ hb) {
    __shared__ int hcnt[NB];
    __shared__ int hcur[NB];
    int tid = threadIdx.x;
    if (blockIdx.x < PART_BLOCKS) {
        // ---------------- partition path ----------------
        for (int b = tid; b < NB; b += 256) hcnt[b] = 0;
        __syncthreads();
        int base = blockIdx.x * PART_CHUNK + tid;
        int ss[PART_EPT], tt[PART_EPT];
#pragma unroll
        for (int k = 0; k < PART_EPT; ++k) {      // phase A: local histogram
            int i = base + k * 256;
            int s = -1, t = 0;
            if (i < E) {
                s = ei[i];
                t = ei[E + i];
                if (s == t) s = -1;               // drop self loops
            }
            ss[k] = s; tt[k] = t;
            if (s >= 0) atomicAdd(&hcnt[t >> 8], 1);
        }
        __syncthreads();
        for (int b = tid; b < NB; b += 256) {     // phase B: reserve ranges
            int c = hcnt[b];
            hcur[b] = b * CAP + (c ? atomicAdd(&gcur[b], c) : 0);
        }
        __syncthreads();
#pragma unroll
        for (int k = 0; k < PART_EPT; ++k) {      // phase C: grouped scatter
            int s = ss[k];
            if (s >= 0) {
                int b = tt[k] >> 8;
                int pos = atomicAdd(&hcur[b], 1);
                if (pos < (b + 1) * CAP)          // safety, statistically never
                    part[pos] = s | ((tt[k] & 255) << 17);
            }
        }
    } else {
        // ---------------- MFMA linear path ----------------
        int lane = tid & 63, wave = tid >> 6;
        int tbase = (blockIdx.x - PART_BLOCKS) * 64 + wave * 16;
        if (tbase >= N) return;                   // wave-uniform
        int r15 = lane & 15, g4 = lane >> 4;
        int arow = tbase + r15;
        if (arow >= N) arow = N - 1;              // clamped load, store guarded
        bf16x8 afr[2];
#pragma unroll
        for (int ks = 0; ks < 2; ++ks) {
            const float* ap = x + arow * 64 + ks * 32 + g4 * 8;
            float4 v0 = *reinterpret_cast<const float4*>(ap);
            float4 v1 = *reinterpret_cast<const float4*>(ap + 4);
            bf16x8 a;
            a[0] = (short)f2bf(v0.x); a[1] = (short)f2bf(v0.y);
            a[2] = (short)f2bf(v0.z); a[3] = (short)f2bf(v0.w);
            a[4] = (short)f2bf(v1.x); a[5] = (short)f2bf(v1.y);
            a[6] = (short)f2bf(v1.z); a[7] = (short)f2bf(v1.w);
            afr[ks] = a;
        }
        f32x4 acc[4] = {};
#pragma unroll
        for (int nt = 0; nt < 4; ++nt)
#pragma unroll
            for (int ks = 0; ks < 2; ++ks) {
                bf16x8 b = *reinterpret_cast<const bf16x8*>(
                    wbf + (nt * 16 + r15) * 64 + ks * 32 + g4 * 8);
                acc[nt] = __builtin_amdgcn_mfma_f32_16x16x32_bf16(afr[ks], b, acc[nt], 0, 0, 0);
            }
#pragma unroll
        for (int r = 0; r < 4; ++r) {
            int node = tbase + g4 * 4 + r;
            if (node < N) {
#pragma unroll
                for (int nt = 0; nt < 4; ++nt)
                    hb[node * D + nt * 16 + r15] = f2bf(acc[nt][r]);
            }
        }
    }
}

// ---- per-bucket CSR build in LDS; emits rc=(start,cnt) and dis ------------
__global__ __launch_bounds__(512) void k_csr(const int* __restrict__ gcur,
                                             const int* __restrict__ part,
                                             int2* __restrict__ rc,
                                             int* __restrict__ srcs,
                                             float* __restrict__ dis) {
    __shared__ int cntL[256];
    __shared__ int scanL[256];
    __shared__ int curL[256];
    int tid = threadIdx.x;
    int b = blockIdx.x;
    if (tid < 256) cntL[tid] = 0;
    __syncthreads();
    int en = gcur[b];
    en = en < CAP ? en : CAP;
    const int* pb = part + b * CAP;
    for (int i = tid; i < en; i += 512)
        atomicAdd(&cntL[pb[i] >> 17], 1);
    __syncthreads();
    if (tid < 256) scanL[tid] = cntL[tid];
    __syncthreads();
    for (int off = 1; off < 256; off <<= 1) {   // inclusive scan over 256
        int v = 0;
        if (tid < 256 && tid >= off) v = scanL[tid - off];
        __syncthreads();
        if (tid < 256) scanL[tid] += v;
        __syncthreads();
    }
    if (tid < 256) {
        int node = b * 256 + tid;
        int excl = scanL[tid] - cntL[tid];
        if (node < N) {
            rc[node] = make_int2(b * CAP + excl, cntL[tid]);
            dis[node] = rsqrtf((float)(cntL[tid] + 1));
        }
        curL[tid] = excl;
    }
    __syncthreads();
    for (int i = tid; i < en; i += 512) {
        int e = pb[i];
        int pos = atomicAdd(&curL[e >> 17], 1);
        srcs[b * CAP + pos] = e & 0x1FFFF;
    }
}

// ---- aggregate: one wave per node, dword-per-lane layout ------------------
// lane = (half = lane>>5 selects edge parity, dl = lane&31 owns dword dl of
// the row = dims 2dl,2dl+1). Two wave-halves process 2 edges/round; 8 edges
// (two 4-slot groups) in flight. Reduction = ONE shfl_down(32) per acc
// (was 24 bpermutes); epilogue = 32-lane coalesced float2 row write.
#define LDE(ii, dv, vv)                                                     \
    {                                                                       \
        int _i = (ii);                                                      \
        int _s = (_i < len) ? srcs[base + _i] : N;   /* N = zero row */     \
        dv = dis[_s];                                                       \
        vv = hb32[_s * 32 + dl];                                            \
    }
#define CONS(dv, vv)                                                        \
    acc0 = fmaf(dv, __uint_as_float((vv) << 16), acc0);                     \
    acc1 = fmaf(dv, __uint_as_float((vv) & 0xffff0000u), acc1);

__global__ __launch_bounds__(256) void k_agg(const int2* __restrict__ rc,
                                             const int* __restrict__ srcs,
                                             const ushort* __restrict__ hb,
                                             const float* __restrict__ dis,
                                             const float* __restrict__ bias,
                                             float* __restrict__ out) {
    int g = blockIdx.x * 256 + threadIdx.x;
    int t = g >> 6, lane = g & 63;
    if (t >= N) return;
    int half = lane >> 5, dl = lane & 31;
    const unsigned* hb32 = reinterpret_cast<const unsigned*>(hb);
    int2 bc = rc[t];
    int base = bc.x, len = bc.y;

    // hoisted tail loads (latency hides under the edge loop)
    float dt = rsqrtf((float)(len + 1));
    unsigned vt = hb32[t * 32 + dl];                   // self row dword
    float2 bb = *reinterpret_cast<const float2*>(bias + 2 * dl);

    float acc0 = 0.f, acc1 = 0.f;

    // group A: edges {half, 2+half, 4+half, 6+half}
    float da0, da1, da2, da3;
    unsigned va0, va1, va2, va3;
    LDE(half,     da0, va0);
    LDE(2 + half, da1, va1);
    LDE(4 + half, da2, va2);
    LDE(6 + half, da3, va3);
    if (len > 8) {                                     // wave-uniform branch
        float db0, db1, db2, db3;
        unsigned vb0, vb1, vb2, vb3;
        LDE(8 + half,  db0, vb0);
        LDE(10 + half, db1, vb1);
        LDE(12 + half, db2, vb2);
        LDE(14 + half, db3, vb3);
        for (int k0 = 16; k0 < len; k0 += 8) {
            float dc0, dc1, dc2, dc3;
            unsigned vc0, vc1, vc2, vc3;
            LDE(k0 + half,     dc0, vc0);
            LDE(k0 + 2 + half, dc1, vc1);
            LDE(k0 + 4 + half, dc2, vc2);
            LDE(k0 + 6 + half, dc3, vc3);
            CONS(da0, va0); CONS(da1, va1); CONS(da2, va2); CONS(da3, va3);
            da0 = db0; va0 = vb0; da1 = db1; va1 = vb1;
            da2 = db2; va2 = vb2; da3 = db3; va3 = vb3;
            db0 = dc0; vb0 = vc0; db1 = dc1; vb1 = vc1;
            db2 = dc2; vb2 = vc2; db3 = dc3; vb3 = vc3;
        }
        CONS(da0, va0); CONS(da1, va1); CONS(da2, va2); CONS(da3, va3);
        CONS(db0, vb0); CONS(db1, vb1); CONS(db2, vb2); CONS(db3, vb3);
    } else {
        CONS(da0, va0); CONS(da1, va1); CONS(da2, va2); CONS(da3, va3);
    }

    // fold the two halves: lanes 0..31 get lane+32's partial
    acc0 += __shfl_down(acc0, 32);
    acc1 += __shfl_down(acc1, 32);
    if (lane < 32) {
        CONS(dt, vt);                                  // self message dt*h[t]
        float2 o;
        o.x = fmaf(dt, acc0, bb.x);
        o.y = fmaf(dt, acc1, bb.y);
        *reinterpret_cast<float2*>(out + t * D + 2 * dl) = o;
    }
}

extern "C" void kernel_launch(void* const* d_in, const int* in_sizes, int n_in,
                              void* d_out, int out_size, void* d_ws, size_t ws_size,
                              hipStream_t stream) {
    const float* x    = (const float*)d_in[0];   // [N, 64]
    const int*   ei   = (const int*)d_in[1];     // [2, E]
    const float* w    = (const float*)d_in[2];   // [64, 64]
    const float* bias = (const float*)d_in[3];   // [64]
    float* out = (float*)d_out;                  // [N, 64]

    // workspace layout (16B aligned)
    char* ws = (char*)d_ws;
    int*    gcur = (int*)(ws);                   // NB ints          @ 0
    ushort* wbf  = (ushort*)(ws + 1664);         // 4096 bf16 (8 KB)
    int*    part = (int*)(ws + 9856);            // NB*CAP ints
    int*    srcs = (int*)(ws + 4814464);         // NB*CAP ints
    int2*   rc   = (int2*)(ws + 9619072);        // N int2 (800 KB)
    float*  dis  = (float*)(ws + 10419072);      // N+1 floats
    ushort* hb   = (ushort*)(ws + 10819200);     // (N+1)*64 bf16

    k_init   <<<1, 256, 0, stream>>>(w, gcur, dis, wbf, hb);
    k_partlin<<<PART_BLOCKS + LIN_BLOCKS, 256, 0, stream>>>(ei, x, wbf, gcur, part, hb);
    k_csr    <<<NB, 512, 0, stream>>>(gcur, part, rc, srcs, dis);
    k_agg    <<<(N * 64) / 256, 256, 0, stream>>>(rc, srcs, hb, dis, bias, out);
}